// Round 1
// baseline (401.540 us; speedup 1.0000x reference)
//
#include <hip/hip_runtime.h>
#include <hip/hip_bf16.h>
#include <math.h>

#define N_NODES 100000
#define N_PAD 100032   // padded row count for workspace feature buffers
#define N_EDGES 1600000
#define HID 128
#define N_CLASS 10

// edge partition params: 256 dst-ranges of 391 nodes (256*391 = 100096)
#define NR2 256
#define RANGE2 391
#define PCAP2 8192     // per-range packed capacity (expected ~6250)
#define P_BLOCKS 512
#define P_SLICE (N_EDGES / P_BLOCKS)  // 3125
#define CAST_ITEMS (N_NODES * (HID / 4))   // 3.2M float4 units
#define CAST_BLOCKS ((CAST_ITEMS + 2047) / 2048)  // 1563
#define WSPLIT_BLOCKS 384                  // 6*16384/256

typedef float f32x4 __attribute__((ext_vector_type(4)));
typedef short short8 __attribute__((ext_vector_type(8)));
typedef unsigned short us4 __attribute__((ext_vector_type(4)));

// bf16 helpers (round-to-nearest-even)
__device__ __forceinline__ unsigned short f2bf(float x) {
    unsigned u = __float_as_uint(x);
    unsigned r = u + 0x7FFF + ((u >> 16) & 1);
    return (unsigned short)(r >> 16);
}
__device__ __forceinline__ float bf2f(unsigned short h) {
    return __uint_as_float(((unsigned)h) << 16);
}
__device__ __forceinline__ float elu(float x) {
    return x > 0.f ? x : (expf(x) - 1.f);
}
__device__ __forceinline__ float4 us4f(us4 v) {
    float4 o;
    o.x = bf2f(v.x); o.y = bf2f(v.y); o.z = bf2f(v.z); o.w = bf2f(v.w);
    return o;
}

// ---------------------------------------------------------------------------
// setup_k: fused edge-partition + x-cast + weight-pack (block-range dispatch).
//   blocks [0,512): 256-way dst-range partition of edges (packed src|dloc<<17)
//   blocks [512,2075): fp32->bf16 cast of x
//   blocks [2075,2459): MLP weight pack to B-frag layout
//   block 2459: fcW pack + row_ptr[N]=E
// gcnt must be zeroed before this kernel (hipMemsetAsync).
// ---------------------------------------------------------------------------
__global__ __launch_bounds__(256) void setup_k(
    const int* __restrict__ src, const int* __restrict__ dst,
    int* __restrict__ gcnt, unsigned* __restrict__ gbuf,
    const float* __restrict__ x, unsigned short* __restrict__ hb,
    const float* __restrict__ Wa, const float* __restrict__ Wb,
    unsigned short* __restrict__ Whp,
    const float* __restrict__ fcW, unsigned short* __restrict__ fcWph,
    int* __restrict__ row_ptr) {
    __shared__ unsigned stash[P_SLICE];
    __shared__ unsigned char rbuf[P_SLICE];
    __shared__ int hist[NR2], cur[NR2], base[NR2];
    const int b = blockIdx.x;
    const int tid = threadIdx.x;

    if (b < P_BLOCKS) {
        // ---- edge partition ----
        hist[tid] = 0;
        cur[tid] = 0;
        __syncthreads();
        const int e0 = b * P_SLICE;
        for (int i = tid; i < P_SLICE; i += 256) {
            unsigned s = (unsigned)src[e0 + i];
            unsigned d = (unsigned)dst[e0 + i];
            unsigned r = d / RANGE2;            // magic-mul
            unsigned dloc = d - r * RANGE2;     // < 391 (9 bits)
            stash[i] = s | (dloc << 17);
            rbuf[i] = (unsigned char)r;
            atomicAdd(&hist[r], 1);
        }
        __syncthreads();
        base[tid] = atomicAdd(&gcnt[tid], hist[tid]);
        __syncthreads();
        for (int i = tid; i < P_SLICE; i += 256) {
            unsigned r = rbuf[i];
            int off = atomicAdd(&cur[r], 1);
            int pos = base[r] + off;
            if (pos < PCAP2) gbuf[(size_t)r * PCAP2 + pos] = stash[i];
        }
    } else if (b < P_BLOCKS + CAST_BLOCKS) {
        // ---- x cast ----
        const int cb = b - P_BLOCKS;
#pragma unroll
        for (int it = 0; it < 8; it++) {
            int i = cb * 2048 + it * 256 + tid;
            if (i < CAST_ITEMS) {
                float4 v = ((const float4*)x)[i];
                us4 o = {f2bf(v.x), f2bf(v.y), f2bf(v.z), f2bf(v.w)};
                ((us4*)hb)[i] = o;
            }
        }
    } else if (b < P_BLOCKS + CAST_BLOCKS + WSPLIT_BLOCKS) {
        // ---- MLP weight pack ----
        int f = (b - P_BLOCKS - CAST_BLOCKS) * 256 + tid;  // < 98304
        int g = f >> 14;
        int r = f & 16383;
        int j = r & 7;
        int L = (r >> 3) & 63;
        int t = r >> 9;
        int kb = t >> 3, nt = t & 7;
        int k = kb * 32 + ((L >> 4) & 3) * 8 + j;
        int n = nt * 16 + (L & 15);
        int layer = g >> 1;
        const float* W = (g & 1) ? Wb : Wa;
        Whp[f] = f2bf(W[layer * 16384 + k * 128 + n]);
    } else {
        // ---- fcW pack + row_ptr tail ----
#pragma unroll
        for (int it = 0; it < 8; it++) {
            int f = it * 256 + tid;  // < 2048
            int j = f & 7;
            int L = (f >> 3) & 63;
            int kb = f >> 9;
            int k = kb * 32 + ((L >> 4) & 3) * 8 + j;
            int n = L & 15;
            fcWph[f] = f2bf((n < N_CLASS) ? fcW[k * N_CLASS + n] : 0.f);
        }
        if (tid == 0) row_ptr[N_NODES] = N_EDGES;
    }
}

// ---------------------------------------------------------------------------
// csort_k: per-range LDS counting sort (self-scans gcnt for col bases).
// row_ptr written here; col written sequentially in full lines.
// ---------------------------------------------------------------------------
__global__ __launch_bounds__(256) void csort_k(const unsigned* __restrict__ gbuf,
                                               const int* __restrict__ gcnt,
                                               int* __restrict__ row_ptr,
                                               int* __restrict__ col) {
    __shared__ int sorted[PCAP2];   // 32 KB
    __shared__ int hist[512];
    __shared__ int cnt[512];
    __shared__ int run[400];
    __shared__ int gsc[NR2];
    const int q = blockIdx.x;
    const int tid = threadIdx.x;

    // self-scan of gcnt -> col base for this range
    gsc[tid] = gcnt[tid];
    __syncthreads();
    for (int off = 1; off < NR2; off <<= 1) {
        int t = (tid >= off) ? gsc[tid - off] : 0;
        __syncthreads();
        gsc[tid] += t;
        __syncthreads();
    }
    const int cb = (q > 0) ? gsc[q - 1] : 0;   // exclusive prefix
    const int n2 = gcnt[q];
    const int node0 = q * RANGE2;
    const unsigned* buf = gbuf + (size_t)q * PCAP2;

    hist[tid] = 0; hist[tid + 256] = 0;
    __syncthreads();
    for (int i = tid; i < n2; i += 256)
        atomicAdd(&hist[buf[i] >> 17], 1);
    __syncthreads();
    cnt[tid] = hist[tid];
    cnt[tid + 256] = hist[tid + 256];
    __syncthreads();
    for (int off = 1; off < 512; off <<= 1) {
        int v0 = (tid >= off) ? hist[tid - off] : 0;
        int v1 = hist[tid + 256 - off];
        __syncthreads();
        hist[tid] += v0;
        hist[tid + 256] += v1;
        __syncthreads();
    }
#pragma unroll
    for (int bb = 0; bb < 2; bb++) {
        int i = tid + 256 * bb;
        if (i < RANGE2) {
            int excl = hist[i] - cnt[i];
            run[i] = excl;
            int node = node0 + i;
            if (node < N_NODES) row_ptr[node] = cb + excl;
        }
    }
    __syncthreads();
    for (int i = tid; i < n2; i += 256) {
        unsigned w = buf[i];
        int pos = atomicAdd(&run[w >> 17], 1);
        sorted[pos] = (int)(w & 0x1FFFF);
    }
    __syncthreads();
    for (int i = tid; i < n2; i += 256) col[cb + i] = sorted[i];
}

// ---------------------------------------------------------------------------
// GEMM2 helper: A from LDS in frag layout (unchanged from previous version).
// ---------------------------------------------------------------------------
__device__ __forceinline__ void gemm_lds(
    const unsigned short* Aph_,
    const unsigned short* __restrict__ Whi_g,
    const float* __restrict__ bias, int tid, f32x4 acc[2][4]) {
    const int L = tid & 63;
    const int w = tid >> 6;
    const int mt0 = (w >> 1) * 2;
    const int nt0 = (w & 1) * 4;
    const int lan15 = L & 15;
#pragma unroll
    for (int n = 0; n < 4; n++) {
        float b = bias[(nt0 + n) * 16 + lan15];
        f32x4 bv = {b, b, b, b};
        acc[0][n] = bv;
        acc[1][n] = bv;
    }
#pragma unroll
    for (int kb = 0; kb < 4; kb++) {
        short8 ah0 = *(const short8*)&Aph_[(((mt0 + 0) * 4 + kb) * 64 + L) * 8];
        short8 ah1 = *(const short8*)&Aph_[(((mt0 + 1) * 4 + kb) * 64 + L) * 8];
#pragma unroll
        for (int n = 0; n < 4; n++) {
            short8 bh = *(const short8*)&Whi_g[((kb * 8 + nt0 + n) * 64 + L) * 8];
            acc[0][n] = __builtin_amdgcn_mfma_f32_16x16x32_bf16(ah0, bh, acc[0][n], 0, 0, 0);
            acc[1][n] = __builtin_amdgcn_mfma_f32_16x16x32_bf16(ah1, bh, acc[1][n], 0, 0, 0);
        }
    }
}

// ---------------------------------------------------------------------------
// layer_k: FUSED aggregation + 2-layer MLP (+ optional final FC).
// Phase 1: each half-wave (32 lanes) aggregates 8 of the block's 64 nodes
//          (self + neighbor sum, fp32 accum from bf16 rows) and writes the
//          bf16 z-row into LDS, row-major [64][256B] with a 16B-chunk XOR
//          swizzle (byte ^= (row&7)<<4) to make the GEMM1 ds_read_b128
//          A-frag reads bank-conflict-free.
// Phase 2: GEMM1 t = ELU(z@Wa+ba) straight from the z LDS tile.
// Phase 3: repack t into frag-layout LDS (same buffer), GEMM2, then either
//          store h (FC=0) or fuse the final FC (FC=1).
// Numerics are bit-identical to the previous split agg_k + mlp path.
// ---------------------------------------------------------------------------
template <int FC>
__global__ __launch_bounds__(256) void layer_k(
    const unsigned short* __restrict__ h,
    const int* __restrict__ row_ptr, const int* __restrict__ col,
    const unsigned short* __restrict__ Wahp,
    const unsigned short* __restrict__ Wbhp,
    const float* __restrict__ ba, const float* __restrict__ bb,
    unsigned short* __restrict__ hout,
    const unsigned short* __restrict__ fcWph,
    const float* __restrict__ fcb, float* __restrict__ out) {
    __shared__ unsigned short Aph[8192];   // 16 KB: z rows, then t frags

    const int tid = threadIdx.x;
    const size_t node_base = (size_t)blockIdx.x * 64;

    // ---- phase 1: aggregate 64 z rows into LDS ----
    {
        const int half = tid >> 5;          // 0..7 within the block
        const int lane = tid & 31;
        const int halfbase = tid & 32;      // shfl base within the wave
        const us4* hp = (const us4*)h;
        for (int s = 0; s < 8; s++) {
            const int mrow = half * 8 + s;            // block-local row 0..63
            const size_t node = node_base + mrow;
            float4 acc = us4f(hp[node * 32 + lane]);  // self term, (1+eps)=1
            if (node < N_NODES) {
                const int beg = row_ptr[node];
                const int end = row_ptr[node + 1];
                for (int base = beg; base < end; base += 32) {
                    const int n = min(32, end - base);
                    int myidx = (lane < n) ? col[base + lane] : 0;
                    int j = 0;
                    for (; j + 8 <= n; j += 8) {
                        int i0 = __shfl(myidx, halfbase + j + 0, 64);
                        int i1 = __shfl(myidx, halfbase + j + 1, 64);
                        int i2 = __shfl(myidx, halfbase + j + 2, 64);
                        int i3 = __shfl(myidx, halfbase + j + 3, 64);
                        int i4 = __shfl(myidx, halfbase + j + 4, 64);
                        int i5 = __shfl(myidx, halfbase + j + 5, 64);
                        int i6 = __shfl(myidx, halfbase + j + 6, 64);
                        int i7 = __shfl(myidx, halfbase + j + 7, 64);
                        float4 v0 = us4f(hp[(size_t)i0 * 32 + lane]);
                        float4 v1 = us4f(hp[(size_t)i1 * 32 + lane]);
                        float4 v2 = us4f(hp[(size_t)i2 * 32 + lane]);
                        float4 v3 = us4f(hp[(size_t)i3 * 32 + lane]);
                        float4 v4 = us4f(hp[(size_t)i4 * 32 + lane]);
                        float4 v5 = us4f(hp[(size_t)i5 * 32 + lane]);
                        float4 v6 = us4f(hp[(size_t)i6 * 32 + lane]);
                        float4 v7 = us4f(hp[(size_t)i7 * 32 + lane]);
                        acc.x += v0.x; acc.y += v0.y; acc.z += v0.z; acc.w += v0.w;
                        acc.x += v1.x; acc.y += v1.y; acc.z += v1.z; acc.w += v1.w;
                        acc.x += v2.x; acc.y += v2.y; acc.z += v2.z; acc.w += v2.w;
                        acc.x += v3.x; acc.y += v3.y; acc.z += v3.z; acc.w += v3.w;
                        acc.x += v4.x; acc.y += v4.y; acc.z += v4.z; acc.w += v4.w;
                        acc.x += v5.x; acc.y += v5.y; acc.z += v5.z; acc.w += v5.w;
                        acc.x += v6.x; acc.y += v6.y; acc.z += v6.z; acc.w += v6.w;
                        acc.x += v7.x; acc.y += v7.y; acc.z += v7.z; acc.w += v7.w;
                    }
                    if (j + 4 <= n) {
                        int i0 = __shfl(myidx, halfbase + j + 0, 64);
                        int i1 = __shfl(myidx, halfbase + j + 1, 64);
                        int i2 = __shfl(myidx, halfbase + j + 2, 64);
                        int i3 = __shfl(myidx, halfbase + j + 3, 64);
                        float4 v0 = us4f(hp[(size_t)i0 * 32 + lane]);
                        float4 v1 = us4f(hp[(size_t)i1 * 32 + lane]);
                        float4 v2 = us4f(hp[(size_t)i2 * 32 + lane]);
                        float4 v3 = us4f(hp[(size_t)i3 * 32 + lane]);
                        acc.x += v0.x; acc.y += v0.y; acc.z += v0.z; acc.w += v0.w;
                        acc.x += v1.x; acc.y += v1.y; acc.z += v1.z; acc.w += v1.w;
                        acc.x += v2.x; acc.y += v2.y; acc.z += v2.z; acc.w += v2.w;
                        acc.x += v3.x; acc.y += v3.y; acc.z += v3.z; acc.w += v3.w;
                        j += 4;
                    }
                    for (; j < n; j++) {
                        int i0 = __shfl(myidx, halfbase + j, 64);
                        float4 v0 = us4f(hp[(size_t)i0 * 32 + lane]);
                        acc.x += v0.x; acc.y += v0.y; acc.z += v0.z; acc.w += v0.w;
                    }
                }
            }
            // bf16 z row -> LDS, swizzled row-major (conflict-free write:
            // fixed XOR per row is a bijection of the 16B chunks)
            us4 o = {f2bf(acc.x), f2bf(acc.y), f2bf(acc.z), f2bf(acc.w)};
            unsigned byte = (unsigned)mrow * 256u +
                            (((unsigned)lane * 8u) ^ (((unsigned)mrow & 7u) << 4));
            *(us4*)((char*)Aph + byte) = o;
        }
    }
    __syncthreads();

    const int L = tid & 63;
    const int w = tid >> 6;
    const int mt0 = (w >> 1) * 2;
    const int nt0 = (w & 1) * 4;
    const int lan15 = L & 15;
    const int quad = L >> 4;

    // ---- GEMM1: t = ELU(z @ Wa + ba), A-frags from swizzled z LDS ----
    f32x4 acc1[2][4];
    {
#pragma unroll
        for (int n = 0; n < 4; n++) {
            float b = ba[(nt0 + n) * 16 + lan15];
            f32x4 bv = {b, b, b, b};
            acc1[0][n] = bv;
            acc1[1][n] = bv;
        }
        const unsigned sw = ((unsigned)lan15 & 7u) << 4;  // == (row&7)<<4
        const unsigned row0 = (unsigned)(mt0 * 16 + lan15) * 256u;
        const unsigned row1 = row0 + 16u * 256u;
#pragma unroll
        for (int kb = 0; kb < 4; kb++) {
            unsigned off = ((unsigned)(kb * 64 + quad * 16)) ^ sw;
            short8 ah0 = *(const short8*)((const char*)Aph + row0 + off);
            short8 ah1 = *(const short8*)((const char*)Aph + row1 + off);
#pragma unroll
            for (int n = 0; n < 4; n++) {
                short8 bh = *(const short8*)&Wahp[((kb * 8 + nt0 + n) * 64 + L) * 8];
                acc1[0][n] = __builtin_amdgcn_mfma_f32_16x16x32_bf16(ah0, bh, acc1[0][n], 0, 0, 0);
                acc1[1][n] = __builtin_amdgcn_mfma_f32_16x16x32_bf16(ah1, bh, acc1[1][n], 0, 0, 0);
            }
        }
    }
    __syncthreads();   // all waves done reading z LDS

    // ---- repack t (bf16) into A-frag LDS (same buffer) ----
#pragma unroll
    for (int i = 0; i < 2; i++) {
#pragma unroll
        for (int n = 0; n < 4; n++) {
            int kdim = (nt0 + n) * 16 + lan15;
            int kb2 = kdim >> 5;
            int q2 = (kdim & 31) >> 3;
            int j2 = kdim & 7;
#pragma unroll
            for (int r = 0; r < 4; r++) {
                float v = elu(acc1[i][n][r]);
                int mrow = quad * 4 + r;
                int idx = (((mt0 + i) * 4 + kb2) * 64 + (mrow + 16 * q2)) * 8 + j2;
                Aph[idx] = f2bf(v);
            }
        }
    }
    __syncthreads();

    // ---- GEMM2: h = ELU(t @ Wb + bb) ----
    {
        f32x4 acc[2][4];
        gemm_lds(Aph, Wbhp, bb, tid, acc);
        if (FC == 0) {
#pragma unroll
            for (int i = 0; i < 2; i++) {
#pragma unroll
                for (int n = 0; n < 4; n++) {
                    int ncol = (nt0 + n) * 16 + lan15;
#pragma unroll
                    for (int r = 0; r < 4; r++) {
                        int mrow = (mt0 + i) * 16 + quad * 4 + r;
                        hout[(node_base + mrow) * HID + ncol] = f2bf(elu(acc[i][n][r]));
                    }
                }
            }
        } else {
            // repack h (bf16, identical rounding to stored-h path) for FC
            __syncthreads();
#pragma unroll
            for (int i = 0; i < 2; i++) {
#pragma unroll
                for (int n = 0; n < 4; n++) {
                    int kdim = (nt0 + n) * 16 + lan15;
                    int kb2 = kdim >> 5;
                    int q2 = (kdim & 31) >> 3;
                    int j2 = kdim & 7;
#pragma unroll
                    for (int r = 0; r < 4; r++) {
                        float v = elu(acc[i][n][r]);
                        int mrow = quad * 4 + r;
                        int idx = (((mt0 + i) * 4 + kb2) * 64 + (mrow + 16 * q2)) * 8 + j2;
                        Aph[idx] = f2bf(v);
                    }
                }
            }
            __syncthreads();
            // FC: waves 0 and 2 handle their 2 M-tiles vs N-tile 0
            if ((w & 1) == 0) {
#pragma unroll
                for (int i = 0; i < 2; i++) {
                    int mt = mt0 + i;
                    float b = (lan15 < N_CLASS) ? fcb[lan15] : 0.f;
                    f32x4 acc2 = {b, b, b, b};
#pragma unroll
                    for (int kb = 0; kb < 4; kb++) {
                        short8 a = *(const short8*)&Aph[((mt * 4 + kb) * 64 + L) * 8];
                        short8 bh = *(const short8*)&fcWph[(kb * 64 + L) * 8];
                        acc2 = __builtin_amdgcn_mfma_f32_16x16x32_bf16(a, bh, acc2, 0, 0, 0);
                    }
#pragma unroll
                    for (int r = 0; r < 4; r++) {
                        size_t node = node_base + mt * 16 + quad * 4 + r;
                        if (node < N_NODES && lan15 < N_CLASS)
                            out[node * N_CLASS + lan15] = acc2[r];
                    }
                }
            }
        }
    }
}

// ---------------------------------------------------------------------------

extern "C" void kernel_launch(void* const* d_in, const int* in_sizes, int n_in,
                              void* d_out, int out_size, void* d_ws, size_t ws_size,
                              hipStream_t stream) {
    const float* x = (const float*)d_in[0];
    const int* ei = (const int*)d_in[1];  // [2][E]
    // d_in[2] = edge_weight (unused by the reference forward)
    const float* Wa = (const float*)d_in[3];   // [3][128][128]
    const float* ba = (const float*)d_in[4];   // [3][128]
    const float* Wb = (const float*)d_in[5];
    const float* bb = (const float*)d_in[6];
    const float* fcW = (const float*)d_in[7];  // [128][10]
    const float* fcb = (const float*)d_in[8];  // [10]
    float* out = (float*)d_out;

    const int* src = ei;
    const int* dst = ei + N_EDGES;

    // workspace carve
    char* w = (char*)d_ws;
    unsigned short* zb = (unsigned short*)w; w += (size_t)N_PAD * HID * 2;  // bf16 h ping
    unsigned short* hb = (unsigned short*)w; w += (size_t)N_PAD * HID * 2;  // bf16 h pong
    int* row_ptr = (int*)w;  w += ((size_t)N_NODES + 8) * 4;
    int* gcnt = (int*)w;     w += NR2 * 4;
    int* col = (int*)w;      w += (size_t)N_EDGES * 4;
    unsigned short* Whp = (unsigned short*)w; w += 6 * 16384 * 2;
    unsigned short* fcWph = (unsigned short*)w; w += 2048 * 2;
    unsigned* gbuf = (unsigned*)w; w += (size_t)NR2 * PCAP2 * 4;  // 8 MB

    // ---- setup: partition + cast + weight pack (one fused kernel) ----
    hipMemsetAsync(gcnt, 0, NR2 * 4, stream);
    const int SETUP_BLOCKS = P_BLOCKS + CAST_BLOCKS + WSPLIT_BLOCKS + 1;
    setup_k<<<SETUP_BLOCKS, 256, 0, stream>>>(src, dst, gcnt, gbuf, x, hb,
                                              Wa, Wb, Whp, fcW, fcWph, row_ptr);
    // ---- counting sort -> CSR ----
    csort_k<<<NR2, 256, 0, stream>>>(gbuf, gcnt, row_ptr, col);

    const int MLP_BLOCKS = (N_NODES + 63) / 64;  // 1563 (ws rows padded)

    // ---- layer 1: fused agg + MLP ----
    layer_k<0><<<MLP_BLOCKS, 256, 0, stream>>>(hb, row_ptr, col,
                                               Whp, Whp + 16384, ba, bb,
                                               zb, nullptr, nullptr, nullptr);
    // ---- layer 2 ----
    layer_k<0><<<MLP_BLOCKS, 256, 0, stream>>>(zb, row_ptr, col,
                                               Whp + 2 * 16384, Whp + 3 * 16384,
                                               ba + 128, bb + 128,
                                               hb, nullptr, nullptr, nullptr);
    // ---- layer 3: fused agg + MLP + final FC ----
    layer_k<1><<<MLP_BLOCKS, 256, 0, stream>>>(hb, row_ptr, col,
                                               Whp + 4 * 16384, Whp + 5 * 16384,
                                               ba + 256, bb + 256,
                                               nullptr, fcWph, fcb, out);
}